// Round 2
// baseline (346.667 us; speedup 1.0000x reference)
//
#include <hip/hip_runtime.h>

#define N_NODES 50000
#define N_EDGES 800000
// IN_F = 64, OUT_F = 64, EDGE_F = 16, d_in1 = 144
// NOTE: harness passes ALL integer inputs as int32 — edge_index is int32[2*E],
// src = ei[e], dst = ei[E+e]. (Round-1 int64-pair indexing caused OOB abort.)

// ---------------------------------------------------------------------------
// pre_kernel: xa = x @ W1[0:64,:], xb = x @ W1[64:128,:]   (N x 64 each)
// One wave per (node-subset, product). Lane j holds W column j in 64 VGPRs.
// ---------------------------------------------------------------------------
__global__ __launch_bounds__(256) void pre_kernel(
    const float* __restrict__ x, const float* __restrict__ W1,
    float* __restrict__ xa, float* __restrict__ xb)
{
    const int w = threadIdx.x >> 6;
    const int j = threadIdx.x & 63;
    const int gw = blockIdx.x * 4 + w;
    const int p = gw & 1;          // 0 -> xa (W1 rows 0..63), 1 -> xb (rows 64..127)
    const int pair = gw >> 1;
    const int npair = (gridDim.x * 4) >> 1;

    float wc[64];
#pragma unroll
    for (int k = 0; k < 64; ++k) wc[k] = W1[(p * 64 + k) * 64 + j];

    float* __restrict__ outp = p ? xb : xa;

    for (int i = pair; i < N_NODES; i += npair) {
        const float4* xr = (const float4*)&x[(long)i * 64];
        float acc = 0.f;
#pragma unroll
        for (int k4 = 0; k4 < 16; ++k4) {
            float4 xv = xr[k4];   // wave-uniform address -> broadcast
            acc += xv.x * wc[k4 * 4 + 0];
            acc += xv.y * wc[k4 * 4 + 1];
            acc += xv.z * wc[k4 * 4 + 2];
            acc += xv.w * wc[k4 * 4 + 3];
        }
        outp[(long)i * 64 + j] = acc;
    }
}

// ---------------------------------------------------------------------------
// edge_kernel: per edge e:
//   h   = relu(xa[src] + xb[dst] + edge_attr[e] @ W1c + b1)
//   msg = h @ W2 + b2
//   atomicAdd(out[dst], msg)
// One wave per 16 edges. Lane j = output feature j. W1c column (16 regs) and
// W2 column (64 regs) in registers; edge_attr and h broadcast via LDS.
// ---------------------------------------------------------------------------
__global__ __launch_bounds__(256) void edge_kernel(
    const float* __restrict__ xa, const float* __restrict__ xb,
    const int* __restrict__ ei,          // int32: src = ei[e], dst = ei[E+e]
    const float* __restrict__ edge_attr,
    const float* __restrict__ W1, const float* __restrict__ b1,
    const float* __restrict__ W2, const float* __restrict__ b2,
    float* __restrict__ out)
{
    __shared__ __align__(16) float eas[4][256];      // 16 edges x 16 attrs per wave
    __shared__ __align__(16) float hs[4][16][64];    // per-edge hidden vector per wave

    const int w = threadIdx.x >> 6;
    const int j = threadIdx.x & 63;
    const int wt = blockIdx.x * 4 + w;   // wave-tile id
    const long eb = (long)wt * 16;       // base edge

    float w1c[16];
    float w2c[64];
#pragma unroll
    for (int k = 0; k < 16; ++k) w1c[k] = W1[(128 + k) * 64 + j];
#pragma unroll
    for (int k = 0; k < 64; ++k) w2c[k] = W2[k * 64 + j];
    const float b1j = b1[j];
    const float b2j = b2[j];

    // lanes 0..15: src of edges eb..eb+15 ; lanes 16..31: dst
    int idxv = 0;
    if (j < 16)       idxv = ei[eb + j];
    else if (j < 32)  idxv = ei[(long)N_EDGES + eb + (j - 16)];

    // stage edge_attr for the 16 edges: 256 floats, contiguous b128 writes
    {
        float4 ev = *(const float4*)&edge_attr[eb * 16 + j * 4];
        *(float4*)&eas[w][j * 4] = ev;
    }

#pragma unroll 4
    for (int e = 0; e < 16; ++e) {
        const int s  = __shfl(idxv, e);
        const int dd = __shfl(idxv, 16 + e);

        float acc = xa[(long)s * 64 + j] + xb[(long)dd * 64 + j] + b1j;
#pragma unroll
        for (int k4 = 0; k4 < 4; ++k4) {
            float4 ev = *(const float4*)&eas[w][e * 16 + k4 * 4];  // uniform -> broadcast
            acc += ev.x * w1c[k4 * 4 + 0];
            acc += ev.y * w1c[k4 * 4 + 1];
            acc += ev.z * w1c[k4 * 4 + 2];
            acc += ev.w * w1c[k4 * 4 + 3];
        }
        const float h = fmaxf(acc, 0.f);
        hs[w][e][j] = h;   // wave-internal write; lgkmcnt orders before reads below

        float msg = b2j;
#pragma unroll
        for (int k4 = 0; k4 < 16; ++k4) {
            float4 hv = *(const float4*)&hs[w][e][k4 * 4];         // uniform -> broadcast
            msg += hv.x * w2c[k4 * 4 + 0];
            msg += hv.y * w2c[k4 * 4 + 1];
            msg += hv.z * w2c[k4 * 4 + 2];
            msg += hv.w * w2c[k4 * 4 + 3];
        }
        unsafeAtomicAdd(&out[(long)dd * 64 + j], msg);
    }
}

// ---------------------------------------------------------------------------
// fallback (only if ws too small): one wave per edge, full 144-dot, shfl GEMM2
// ---------------------------------------------------------------------------
__global__ __launch_bounds__(256) void fallback_kernel(
    const float* __restrict__ x, const int* __restrict__ ei,
    const float* __restrict__ edge_attr,
    const float* __restrict__ W1, const float* __restrict__ b1,
    const float* __restrict__ W2, const float* __restrict__ b2,
    float* __restrict__ out)
{
    const int w = threadIdx.x >> 6;
    const int j = threadIdx.x & 63;
    const long e = (long)blockIdx.x * 4 + w;
    if (e >= N_EDGES) return;
    const int s  = ei[e];
    const int dd = ei[(long)N_EDGES + e];

    float acc = b1[j];
    for (int k = 0; k < 64; ++k) acc += x[(long)s  * 64 + k] * W1[k * 64 + j];
    for (int k = 0; k < 64; ++k) acc += x[(long)dd * 64 + k] * W1[(64 + k) * 64 + j];
    for (int k = 0; k < 16; ++k) acc += edge_attr[e * 16 + k] * W1[(128 + k) * 64 + j];
    const float h = fmaxf(acc, 0.f);

    float msg = b2[j];
    for (int k = 0; k < 64; ++k) msg += __shfl(h, k) * W2[k * 64 + j];
    unsafeAtomicAdd(&out[(long)dd * 64 + j], msg);
}

extern "C" void kernel_launch(void* const* d_in, const int* in_sizes, int n_in,
                              void* d_out, int out_size, void* d_ws, size_t ws_size,
                              hipStream_t stream) {
    const float* x   = (const float*)d_in[0];
    const int*   ei  = (const int*)d_in[1];   // int32 (harness converts int64)
    const float* ea  = (const float*)d_in[2];
    const float* W1  = (const float*)d_in[3];
    const float* b1  = (const float*)d_in[4];
    const float* W2  = (const float*)d_in[5];
    const float* b2  = (const float*)d_in[6];
    float* out = (float*)d_out;

    // out is re-poisoned before every launch; atomics need zeros
    hipMemsetAsync(out, 0, (size_t)N_NODES * 64 * sizeof(float), stream);

    const size_t need = (size_t)2 * N_NODES * 64 * sizeof(float);
    if (ws_size >= need) {
        float* xauf = (float*)d_ws;
        float* xbuf = xauf + (size_t)N_NODES * 64;
        pre_kernel<<<512, 256, 0, stream>>>(x, W1, xauf, xbuf);
        edge_kernel<<<N_EDGES / 64, 256, 0, stream>>>(xauf, xbuf, ei, ea,
                                                      W1, b1, W2, b2, out);
    } else {
        fallback_kernel<<<N_EDGES / 4, 256, 0, stream>>>(x, ei, ea,
                                                         W1, b1, W2, b2, out);
    }
}